// Round 1
// 465.481 us; speedup vs baseline: 1.0941x; 1.0941x over previous
//
#include <hip/hip_runtime.h>

#define H 51
#define TIN 512
#define TTOT 544      // TIN + future(32)
#define BTILE 8
#define AST 72        // ring row stride in shorts (144 B)
#define H2ST 13       // sH2f row stride in floats (13 coprime 32)
#define SOST 548      // sOut row stride in floats (mult of 4 for b128, 548%32=4)

typedef __attribute__((ext_vector_type(8))) short short8;
typedef __attribute__((ext_vector_type(4))) float float4v;

#define MFMA __builtin_amdgcn_mfma_f32_16x16x32_bf16

__device__ __forceinline__ float fast_rcp(float x) { return __builtin_amdgcn_rcpf(x); }
__device__ __forceinline__ float sigf(float x)  { return fast_rcp(1.0f + __expf(-x)); }
__device__ __forceinline__ float tanhf_(float x){ return 1.0f - 2.0f * fast_rcp(1.0f + __expf(2.0f * x)); }

__device__ __forceinline__ unsigned short bf16rnd(float x) {
    unsigned int u = __float_as_uint(x);
    return (unsigned short)((u + 0x7fffu + ((u >> 16) & 1u)) >> 16);
}
__device__ __forceinline__ void bf16split(float x, unsigned short& hi, float& lo) {
    unsigned int u  = __float_as_uint(x);
    unsigned int hr = (u + 0x7fffu + ((u >> 16) & 1u)) & 0xffff0000u;
    hi = (unsigned short)(hr >> 16);
    lo = x - __uint_as_float(hr);          // exact residual
}

// L1 k-space (A = sA1): 0..50 h1 | 51 x | 52..63 zero.
__device__ __forceinline__ float b1val(int k, int u, int g,
                                       const float* Whh1, const float* Wih1) {
    if (u >= H) return 0.0f;
    const int r = g * H + u;
    if (k < H)  return Whh1[r * H + k];
    if (k == H) return Wih1[r];
    return 0.0f;
}
// L2 k-space: 0..50 h1 (sA1) | 51..63 zero | 64..114 h2 (sA2 cols 0..50).
__device__ __forceinline__ float b2val(int k, int u, int g,
                                       const float* Wih2, const float* Whh2) {
    if (u >= H) return 0.0f;
    const int r = g * H + u;
    if (k < H) return Wih2[r * H + k];
    if (k >= 64 && k < 64 + H) return Whh2[r * H + (k - 64)];
    return 0.0f;
}

// R15 = R14 with the step loop made LDS-only and the act-spread deleted:
//  (1) input tile (8x512) staged to LDS once; out (8x544) buffered in LDS and
//      written back float4 at the end -> no global ops (so no vmcnt(0) drain)
//      inside the 544-step loop.
//  (2) relocated A-ring rows: quad q writes its 2 batch rows to A-rows 4q,4q+1
//      (batch b in {2,3,6,7} -> row b+6). Each quad consumes its own MFMA regs
//      0,1 directly; the 8 shfl_xor + 8 cndmask act-spread per wave per step is
//      gone. D-rows 2,3,6,7 were never read by anyone. Bit-identical numerics.
//  (3) headw moved before l1work (its sH2f slot was written last step) so the
//      5-deep shuffle-reduce hides under MFMA issue.
// Revert point if absmax > 1.0254e-3 or slower: R14 (509 us).
__global__ __launch_bounds__(512)
__attribute__((amdgpu_waves_per_eu(2, 2)))
void lstm_seq(
    const float* __restrict__ input,   // [2048][512]
    const float* __restrict__ W_ih1,   // [204]
    const float* __restrict__ W_hh1,   // [204][51]
    const float* __restrict__ b_ih1,   // [204]
    const float* __restrict__ b_hh1,   // [204]
    const float* __restrict__ W_ih2,   // [204][51]
    const float* __restrict__ W_hh2,   // [204][51]
    const float* __restrict__ b_ih2,   // [204]
    const float* __restrict__ b_hh2,   // [204]
    const float* __restrict__ W_lin,   // [51]
    const float* __restrict__ b_lin,   // [1]
    float* __restrict__ out)           // [2048][544]
{
    __shared__ __align__(16) unsigned short sA1h[2][16][AST];  // h1 ring + x col 51
    __shared__ __align__(16) unsigned short sA2h[2][16][AST];  // h2 ring
    __shared__ float sH2f[2][64][H2ST];                        // h2 f32 for head
    __shared__ __align__(8) float sXlo[2][8];                  // x bf16-residual
    __shared__ float sWlin[64];
    __shared__ __align__(16) float sIn[BTILE][TIN];            // staged input tile
    __shared__ __align__(16) float sOut[BTILE][SOST];          // buffered outputs

    const int tid  = threadIdx.x;
    const int lane = tid & 63;
    const int wv   = tid >> 6;             // 0..7
    const int Lw   = wv >> 2;              // 0: L1+head waves, 1: L2 waves
    const int ut   = wv & 3;
    const int quad = lane >> 4;
    const int kq   = quad * 8;
    const int nl   = lane & 15;
    const int u    = ut * 16 + nl;
    const int ur   = (u < H) ? u : (H - 1);
    const int b0   = blockIdx.x * BTILE;
    const float blin = b_lin[0];
    const int rowA = (quad & 1) * 4 + (quad >> 1) * 2;   // this quad's 2 batch-rows
    const int arow = quad * 4;             // A-ring row this quad WRITES (relocated)
    const int kc   = lane & 31;            // head: k-phase
    const int bhead= 2 * ut + (lane >> 5); // head: this lane's batch

    // ---- LDS init + input staging ----
    {
        unsigned short* p0 = &sA1h[0][0][0];
        unsigned short* p2 = &sA2h[0][0][0];
        for (int i = tid; i < 2 * 16 * AST; i += 512) { p0[i] = 0; p2[i] = 0; }
        float* pf = &sH2f[0][0][0];
        for (int i = tid; i < 2 * 64 * H2ST; i += 512) pf[i] = 0.0f;
        if (tid < 16) sXlo[tid >> 3][tid & 7] = 0.0f;
        if (tid < 64) sWlin[tid] = (tid < H) ? W_lin[tid] : 0.0f;
        // stage input tile: 8 rows x 512 f32, coalesced float4 (2 per thread)
        const int r = tid >> 6, l = tid & 63;
        const float* src = input + (size_t)(b0 + r) * TIN;
        *(float4v*)&sIn[r][l * 4]       = *(const float4v*)&src[l * 4];
        *(float4v*)&sIn[r][256 + l * 4] = *(const float4v*)&src[256 + l * 4];
    }
    __syncthreads();
    if (tid < 8) {   // x(0) -> slot 0: bf16 hi in A col 51 (relocated row), residual in sXlo
        unsigned short hh; float lo;
        bf16split(sIn[tid][0], hh, lo);
        sA1h[0][(tid & 2) ? tid + 6 : tid][51] = hh;
        sXlo[0][tid] = lo;
    }
    __syncthreads();

    if (Lw == 0) {
        // ================= LAYER-1 + HEAD WAVES =================
        short8 B1h[4][2];
        float zb1[4], wxf[4];
        #pragma unroll
        for (int g = 0; g < 4; ++g) {
            #pragma unroll
            for (int kt = 0; kt < 2; ++kt)
                #pragma unroll
                for (int j = 0; j < 8; ++j)
                    B1h[g][kt][j] = (short)bf16rnd(b1val(kt * 32 + kq + j, u, g, W_hh1, W_ih1));
            const int r = g * H + ur;
            zb1[g] = b_ih1[r] + b_hh1[r];
            wxf[g] = W_ih1[r];             // f32 x-weight for residual fix
        }
        float c1[2] = {0, 0};

        auto l1work = [&](int rs, int ws) __attribute__((always_inline)) {
            short8 a0h = *(const short8*)&sA1h[rs][nl][kq];
            short8 a1h = *(const short8*)&sA1h[rs][nl][32 + kq];
            float2 xl = *(const float2*)&sXlo[rs][rowA];   // residuals for my 2 rows
            float4v C[4];
            #pragma unroll
            for (int g = 0; g < 4; ++g) {
                float4v c = {zb1[g], zb1[g], zb1[g], zb1[g]};
                c = MFMA(a0h, B1h[g][0], c, 0, 0, 0);
                c = MFMA(a1h, B1h[g][1], c, 0, 0, 0);
                C[g] = c;
            }
            float h1v[2];
            #pragma unroll
            for (int j = 0; j < 2; ++j) {
                const float xr = j ? xl.y : xl.x;
                float I = sigf  (C[0][j] + wxf[0] * xr);
                float F = sigf  (C[1][j] + wxf[1] * xr);
                float G = tanhf_(C[2][j] + wxf[2] * xr);
                float O = sigf  (C[3][j] + wxf[3] * xr);
                c1[j] = F * c1[j] + I * G;
                h1v[j] = O * tanhf_(c1[j]);
            }
            if (u < H) {
                #pragma unroll
                for (int j = 0; j < 2; ++j)
                    sA1h[ws][arow + j][u] = bf16rnd(h1v[j]);
            }
        };
        auto headw = [&](int slot, int outt) __attribute__((always_inline)) -> float {
            float p = sWlin[kc]      * sH2f[slot][kc][bhead]
                    + sWlin[kc + 32] * sH2f[slot][kc + 32][bhead];
            p += __shfl_xor(p, 1);  p += __shfl_xor(p, 2);  p += __shfl_xor(p, 4);
            p += __shfl_xor(p, 8);  p += __shfl_xor(p, 16);
            float val = p + blin;
            if (kc == 0) sOut[bhead][outt] = val;
            return val;
        };
        auto teach = [&](int s, int rs, int ws) __attribute__((always_inline)) {
            float xpre = 0.0f;
            const bool doX = (wv == 1) && (lane < 8) && (s + 1 < TIN);
            if (doX) xpre = sIn[lane][s + 1];
            if (s >= 2) headw(ws, s - 2);      // sH2f[ws] written last step
            l1work(rs, ws);
            if (doX) {
                unsigned short hh; float lo; bf16split(xpre, hh, lo);
                sA1h[ws][(lane & 2) ? lane + 6 : lane][51] = hh;
                sXlo[ws][lane] = lo;
            }
            __syncthreads();
        };

        // ---- pipelined teacher-forced phase (static rs/ws) ----
        for (int s = 0; s < TIN; ++s) {
            if ((s & 1) == 0) teach(s, 0, 1);
            else              teach(s, 1, 0);
        }
        // ---- serial autoregressive tail ----
        for (int s = TIN; s <= TTOT; ++s) {
            const int rs = s & 1, ws = rs ^ 1;
            __syncthreads();               // B1: L2 finished h2(s-1) -> sH2f[rs]
            {
                float val = headw(rs, s - 1);
                if (kc == 0) {             // feedback x(s) = out(s-1)
                    unsigned short hh; float lo; bf16split(val, hh, lo);
                    sA1h[rs][(bhead & 2) ? bhead + 6 : bhead][51] = hh;
                    sXlo[rs][bhead] = lo;
                }
                if (s == TIN) headw(ws, s - 2);   // gap: out(TIN-2)
            }
            __syncthreads();               // B2: x(s) visible
            if (s < TTOT) l1work(rs, ws);
            __syncthreads();               // B3: h1(s) visible
        }
    } else {
        // ================= LAYER-2 WAVES =================
        short8 B2h[4][4];
        float zb2[4];
        #pragma unroll
        for (int g = 0; g < 4; ++g) {
            #pragma unroll
            for (int kt = 0; kt < 4; ++kt)
                #pragma unroll
                for (int j = 0; j < 8; ++j)
                    B2h[g][kt][j] = (short)bf16rnd(b2val(kt * 32 + kq + j, u, g, W_ih2, W_hh2));
            const int r = g * H + ur;
            zb2[g] = b_ih2[r] + b_hh2[r];
        }
        float c2[2] = {0, 0};

        auto l2work = [&](int rs, int ws) __attribute__((always_inline)) {
            short8 f0h = *(const short8*)&sA1h[rs][nl][kq];
            short8 f1h = *(const short8*)&sA1h[rs][nl][32 + kq];
            short8 f2h = *(const short8*)&sA2h[rs][nl][kq];
            short8 f3h = *(const short8*)&sA2h[rs][nl][32 + kq];
            float4v C[4];
            #pragma unroll
            for (int g = 0; g < 4; ++g) {
                float4v c = {zb2[g], zb2[g], zb2[g], zb2[g]};
                c = MFMA(f0h, B2h[g][0], c, 0, 0, 0);
                c = MFMA(f1h, B2h[g][1], c, 0, 0, 0);
                c = MFMA(f2h, B2h[g][2], c, 0, 0, 0);
                c = MFMA(f3h, B2h[g][3], c, 0, 0, 0);
                C[g] = c;
            }
            float h2v[2];
            #pragma unroll
            for (int j = 0; j < 2; ++j) {
                float I = sigf  (C[0][j]);
                float F = sigf  (C[1][j]);
                float G = tanhf_(C[2][j]);
                float O = sigf  (C[3][j]);
                c2[j] = F * c2[j] + I * G;
                h2v[j] = O * tanhf_(c2[j]);
            }
            if (u < H) {
                #pragma unroll
                for (int j = 0; j < 2; ++j) {
                    sA2h[ws][arow + j][u] = bf16rnd(h2v[j]);
                    sH2f[rs][u][rowA + j] = h2v[j];
                }
            }
        };

        // ---- pipelined teacher-forced phase ----
        for (int s = 0; s < TIN; ++s) {
            if ((s & 1) == 0) { if (s) l2work(0, 1); }
            else              l2work(1, 0);
            __syncthreads();
        }
        // ---- serial tail ----
        for (int s = TIN; s <= TTOT; ++s) {
            const int rs = s & 1, ws = rs ^ 1;
            l2work(rs, ws);
            __syncthreads();               // B1
            __syncthreads();               // B2
            __syncthreads();               // B3
        }
    }

    // ---- write buffered outputs back: 8 rows x 544 f32, float4 coalesced ----
    __syncthreads();
    for (int i = tid; i < BTILE * (TTOT / 4); i += 512) {
        const int r = i / (TTOT / 4);
        const int c = i - r * (TTOT / 4);
        *(float4v*)&out[(size_t)(b0 + r) * TTOT + c * 4] =
            *(const float4v*)&sOut[r][c * 4];
    }
}

extern "C" void kernel_launch(void* const* d_in, const int* in_sizes, int n_in,
                              void* d_out, int out_size, void* d_ws, size_t ws_size,
                              hipStream_t stream) {
    const float* input = (const float*)d_in[0];
    const float* W_ih1 = (const float*)d_in[1];
    const float* W_hh1 = (const float*)d_in[2];
    const float* b_ih1 = (const float*)d_in[3];
    const float* b_hh1 = (const float*)d_in[4];
    const float* W_ih2 = (const float*)d_in[5];
    const float* W_hh2 = (const float*)d_in[6];
    const float* b_ih2 = (const float*)d_in[7];
    const float* b_hh2 = (const float*)d_in[8];
    const float* b_lin = (const float*)d_in[10];
    const float* W_lin = (const float*)d_in[9];
    // d_in[11] = future (=32), compiled in.
    float* out = (float*)d_out;

    lstm_seq<<<dim3(256), dim3(512), 0, stream>>>(input, W_ih1, W_hh1, b_ih1, b_hh1,
                                                  W_ih2, W_hh2, b_ih2, b_hh2,
                                                  W_lin, b_lin, out);
}